// Round 2
// baseline (56720.081 us; speedup 1.0000x reference)
//
#include <hip/hip_runtime.h>
#include <cstdint>

#define TT 256
#define BB 128
#define HH 256
#define LL 3
#define LN_EPS 1e-5f

// ---------------- helpers ----------------

__device__ __forceinline__ float fast_sigmoid(float x) {
    return 1.f / (1.f + __expf(-x));
}
__device__ __forceinline__ float fast_tanh(float x) {
    float xc = fminf(fmaxf(x, -15.f), 15.f);
    float e = __expf(2.f * xc);
    return 1.f - 2.f / (e + 1.f);
}
__device__ __forceinline__ float relu(float x) { return fmaxf(x, 0.f); }

// block-wide dual reduction over 512 threads (8 waves of 64)
__device__ __forceinline__ float2 red2(float a, float b, float* scr, int tid) {
#pragma unroll
    for (int o = 32; o > 0; o >>= 1) {
        a += __shfl_down(a, o);
        b += __shfl_down(b, o);
    }
    int w = tid >> 6;
    if ((tid & 63) == 0) { scr[w] = a; scr[8 + w] = b; }
    __syncthreads();
    if (tid == 0) {
        float s = 0.f, s2 = 0.f;
#pragma unroll
        for (int i = 0; i < 8; i++) { s += scr[i]; s2 += scr[8 + i]; }
        scr[16] = s; scr[17] = s2;
    }
    __syncthreads();
    float2 r; r.x = scr[16]; r.y = scr[17];
    __syncthreads();   // protect scr before next red2 call
    return r;
}

// y_raw[n] = sum_k xs[k] * W[k][n]; W fp32 row-major [K,N], read as float2
// column pairs. G = K-split groups; partials written to dst[g*N + n].
// No bias (consumer adds).
template <int K, int N, int G>
__device__ __forceinline__ void matvec(const float* __restrict__ Wp,
                                       const float* __restrict__ xs,
                                       float* __restrict__ dst, int t) {
    constexpr int nP = N / 2;
    constexpr int slots = nP * G;
    if ((unsigned)t < (unsigned)slots) {
        int g = t / nP;            // nP is constexpr pow2 -> shift
        int j = t - g * nP;
        constexpr int kc = K / G;
        const float2* W = (const float2*)Wp + (size_t)g * kc * nP + j;
        const float* xp = xs + g * kc;
        float a0 = 0.f, a1 = 0.f;
#pragma unroll 4
        for (int k = 0; k < kc; k++) {
            float2 w = W[(size_t)k * nP];
            float xk = xp[k];
            a0 = fmaf(w.x, xk, a0);
            a1 = fmaf(w.y, xk, a1);
        }
        dst[g * N + 2 * j]     = a0;
        dst[g * N + 2 * j + 1] = a1;
    }
}

// ---------------- main kernel ----------------

struct Args {
    const float *params, *disp;
    const float *embed_b, *embed_g, *embed_beta;
    const float *skip_b;
    const float *gates_b;
    const float *inln_g, *inln_b, *hln_g, *hln_b, *sln_g, *sln_b;
    const float *ab1, *aw2, *ab2;
    const float *rb1, *rb2, *rln_g, *rln_b;
    const float *ob1, *oln_g, *oln_b, *ow2, *ob2;
    const float *gw, *a1w, *r1w, *r2w, *ew, *sw, *o1w;
    float* out;
};

__global__ __launch_bounds__(512) void xlstm_kernel(Args A) {
    const int tid = threadIdx.x;
    const int b = blockIdx.x;

    __shared__ float xv[HH];            // current x
    __shared__ float hs[LL * HH];       // h state
    __shared__ float cs[LL * HH];       // c state
    __shared__ float xnhn[2 * HH];      // [xn, hn] gates input; reused as rbuf/head input
    __shared__ float g4[1024];          // gates out / matvec partial scratch
    __shared__ float vtmp[HH];          // embed raw
    __shared__ float sk[128];           // skip activation
    __shared__ float skraw[128];        // skip raw
    __shared__ float xt[17];            // timestep input features
    __shared__ float scr[20];           // reduction scratch

    for (int i = tid; i < LL * HH; i += 512) { hs[i] = 0.f; cs[i] = 0.f; }
    if (tid < 16) xt[1 + tid] = A.params[b * 16 + tid];
    __syncthreads();

    for (int t = 0; t < TT; t++) {
        if (tid == 0) xt[0] = A.disp[b * TT + t];
        __syncthreads();

        // skip (threads 0..63) and embed (threads 64..191), concurrently
        matvec<17, 128, 1>(A.sw, xt, skraw, tid);
        matvec<17, 256, 1>(A.ew, xt, vtmp, tid - 64);
        __syncthreads();

        if (tid >= 256 && tid < 384) {
            int m = tid - 256;
            sk[m] = relu(skraw[m] + A.skip_b[m]);
        }
        float v = (tid < HH) ? vtmp[tid] + A.embed_b[tid] : 0.f;
        float2 f2 = red2(v, v * v, scr, tid);
        float mu = f2.x / HH;
        float inv = rsqrtf(f2.y / HH - mu * mu + LN_EPS);
        if (tid < HH) xv[tid] = relu((v - mu) * inv * A.embed_g[tid] + A.embed_beta[tid]);
        __syncthreads();

        for (int l = 0; l < LL; l++) {
            float* hl = hs + l * HH;
            float* cl = cs + l * HH;

            // xn = LN(x)
            v = (tid < HH) ? xv[tid] : 0.f;
            f2 = red2(v, v * v, scr, tid);
            mu = f2.x / HH; inv = rsqrtf(f2.y / HH - mu * mu + LN_EPS);
            if (tid < HH) xnhn[tid] = (v - mu) * inv * A.inln_g[l * HH + tid] + A.inln_b[l * HH + tid];

            // hn = LN(h_prev)
            v = (tid < HH) ? hl[tid] : 0.f;
            f2 = red2(v, v * v, scr, tid);
            mu = f2.x / HH; inv = rsqrtf(f2.y / HH - mu * mu + LN_EPS);
            if (tid < HH) xnhn[HH + tid] = (v - mu) * inv * A.hln_g[l * HH + tid] + A.hln_b[l * HH + tid];
            __syncthreads();

            // imp = sigmoid(tanh(c_prev @ aw1 + ab1) @ aw2 + ab2)
            matvec<256, 256, 4>(A.a1w + (size_t)l * (256 * 256), cl, g4, tid);
            __syncthreads();
            v = 0.f;
            if (tid < HH) {
                float s = g4[tid] + g4[HH + tid] + g4[2 * HH + tid] + g4[3 * HH + tid] + A.ab1[l * HH + tid];
                v = fast_tanh(s) * A.aw2[l * HH + tid];
            }
            f2 = red2(v, 0.f, scr, tid);
            float impv = fast_sigmoid(f2.x + A.ab2[l]);

            // gates = [xn, hn] @ gates_w  (g4 overwrite safe: red2 synced)
            matvec<512, 1024, 1>(A.gw + (size_t)l * (512 * 1024), xnhn, g4, tid);
            __syncthreads();

            float o = 0.f;
            v = 0.f;
            if (tid < HH) {
                const float* gb = A.gates_b + l * 1024;
                float ig = fast_sigmoid(g4[tid] + gb[tid]);
                float fg = fast_sigmoid(g4[256 + tid] + gb[256 + tid]);
                float gg = fast_tanh(g4[512 + tid] + gb[512 + tid]);
                o = fast_sigmoid(g4[768 + tid] + gb[768 + tid]);
                v = (fg * cl[tid] + ig * gg) * impv;     // c_raw
            }
            f2 = red2(v, v * v, scr, tid);
            mu = f2.x / HH; inv = rsqrtf(f2.y / HH - mu * mu + LN_EPS);
            if (tid < HH) {
                float cn = (v - mu) * inv * A.sln_g[l * HH + tid] + A.sln_b[l * HH + tid];
                cl[tid] = cn;
                hl[tid] = o * fast_tanh(cn);
            }
            __syncthreads();

            // residual MLP: relu(h @ rw1 + rb1) @ rw2 + rb2; x = LN(rb + h) + residual
            matvec<256, 512, 2>(A.r1w + (size_t)l * (256 * 512), hl, g4, tid);
            __syncthreads();
            if (tid < 512) xnhn[tid] = relu(g4[tid] + g4[512 + tid] + A.rb1[l * 512 + tid]);
            __syncthreads();
            matvec<512, 256, 4>(A.r2w + (size_t)l * (512 * 256), xnhn, g4, tid);
            __syncthreads();
            v = 0.f;
            if (tid < HH)
                v = g4[tid] + g4[HH + tid] + g4[2 * HH + tid] + g4[3 * HH + tid]
                    + A.rb2[l * HH + tid] + hl[tid];
            f2 = red2(v, v * v, scr, tid);
            mu = f2.x / HH; inv = rsqrtf(f2.y / HH - mu * mu + LN_EPS);
            if (tid < HH) xv[tid] = (v - mu) * inv * A.rln_g[l * HH + tid] + A.rln_b[l * HH + tid] + xv[tid];
            __syncthreads();
        }

        // output head: y = [x, skip] @ ow1 -> LN -> relu -> @ ow2 + ob2
        if (tid < HH) xnhn[tid] = xv[tid];
        else if (tid < HH + 128) xnhn[tid] = sk[tid - HH];
        __syncthreads();
        matvec<384, 128, 8>(A.o1w, xnhn, g4, tid);
        __syncthreads();
        v = 0.f;
        if (tid < 128) {
            float s = 0.f;
#pragma unroll
            for (int g = 0; g < 8; g++) s += g4[g * 128 + tid];
            v = s + A.ob1[tid];
        }
        f2 = red2(v, v * v, scr, tid);
        mu = f2.x / 128.f; inv = rsqrtf(f2.y / 128.f - mu * mu + LN_EPS);
        float contrib = 0.f;
        if (tid < 128) contrib = relu((v - mu) * inv * A.oln_g[tid] + A.oln_b[tid]) * A.ow2[tid];
        f2 = red2(contrib, 0.f, scr, tid);
        if (tid == 0) A.out[b * TT + t] = f2.x + A.ob2[0];
        __syncthreads();   // protect xt / g4 / xnhn for next iter
    }
}

// ---------------- launch ----------------

extern "C" void kernel_launch(void* const* d_in, const int* in_sizes, int n_in,
                              void* d_out, int out_size, void* d_ws, size_t ws_size,
                              hipStream_t stream) {
    // d_in order (setup_inputs dict order):
    //  0 params [128,16]      1 disp [128,256]
    //  2 embed_w [17,256]     3 embed_b [256]   4 embed_g [256]   5 embed_beta [256]
    //  6 skip_w [17,128]      7 skip_b [128]
    //  8 gates_w [3,512,1024] 9 gates_b [3,1024]
    // 10 inln_g [3,256] 11 inln_b 12 hln_g 13 hln_b 14 sln_g 15 sln_b
    // 16 aw1 [3,256,256] 17 ab1 [3,256] 18 aw2 [3,256,1] 19 ab2 [3,1]
    // 20 rw1 [3,256,512] 21 rb1 [3,512] 22 rw2 [3,512,256] 23 rb2 [3,256]
    // 24 rln_g [3,256] 25 rln_b [3,256]
    // 26 ow1 [384,128] 27 ob1 [128] 28 oln_g [128] 29 oln_b [128]
    // 30 ow2 [128,1] 31 ob2 [1]

    Args A;
    A.params     = (const float*)d_in[0];
    A.disp       = (const float*)d_in[1];
    A.ew         = (const float*)d_in[2];
    A.embed_b    = (const float*)d_in[3];
    A.embed_g    = (const float*)d_in[4];
    A.embed_beta = (const float*)d_in[5];
    A.sw         = (const float*)d_in[6];
    A.skip_b     = (const float*)d_in[7];
    A.gw         = (const float*)d_in[8];
    A.gates_b    = (const float*)d_in[9];
    A.inln_g     = (const float*)d_in[10];
    A.inln_b     = (const float*)d_in[11];
    A.hln_g      = (const float*)d_in[12];
    A.hln_b      = (const float*)d_in[13];
    A.sln_g      = (const float*)d_in[14];
    A.sln_b      = (const float*)d_in[15];
    A.a1w        = (const float*)d_in[16];
    A.ab1        = (const float*)d_in[17];
    A.aw2        = (const float*)d_in[18];
    A.ab2        = (const float*)d_in[19];
    A.r1w        = (const float*)d_in[20];
    A.rb1        = (const float*)d_in[21];
    A.r2w        = (const float*)d_in[22];
    A.rb2        = (const float*)d_in[23];
    A.rln_g      = (const float*)d_in[24];
    A.rln_b      = (const float*)d_in[25];
    A.o1w        = (const float*)d_in[26];
    A.ob1        = (const float*)d_in[27];
    A.oln_g      = (const float*)d_in[28];
    A.oln_b      = (const float*)d_in[29];
    A.ow2        = (const float*)d_in[30];
    A.ob2        = (const float*)d_in[31];
    A.out        = (float*)d_out;

    xlstm_kernel<<<BB, 512, 0, stream>>>(A);
}

// Round 3
// 48466.254 us; speedup vs baseline: 1.1703x; 1.1703x over previous
//
#include <hip/hip_runtime.h>
#include <cstdint>

#define TT 256
#define BB 128
#define HH 256
#define LL 3
#define LN_EPS 1e-5f

// ---------------- helpers ----------------

__device__ __forceinline__ float fast_sigmoid(float x) {
    return 1.f / (1.f + __expf(-x));
}
__device__ __forceinline__ float fast_tanh(float x) {
    float xc = fminf(fmaxf(x, -15.f), 15.f);
    float e = __expf(2.f * xc);
    return 1.f - 2.f / (e + 1.f);
}
__device__ __forceinline__ float relu(float x) { return fmaxf(x, 0.f); }

// dual reduction over 1024 threads (16 waves). One barrier; every thread
// sums the 16 wave-partials itself (LDS broadcast reads). Caller must
// ping-pong the scr buffer between consecutive calls.
__device__ __forceinline__ float2 red2(float a, float b, float* scr, int tid) {
#pragma unroll
    for (int o = 32; o > 0; o >>= 1) {
        a += __shfl_down(a, o);
        b += __shfl_down(b, o);
    }
    if ((tid & 63) == 0) { int w = tid >> 6; scr[w] = a; scr[16 + w] = b; }
    __syncthreads();
    float s = 0.f, s2 = 0.f;
#pragma unroll
    for (int i = 0; i < 16; i++) { s += scr[i]; s2 += scr[16 + i]; }
    return make_float2(s, s2);
}

// y_raw[n] = sum_k xs[k]*W[k][n]; W fp32 row-major [K,N] read as float4
// (4 columns per thread). G-way K-split; partials to dst[g*N + n].
// nQ*G should equal 1024 (all threads busy). No bias (consumer adds).
template <int K, int N, int G>
__device__ __forceinline__ void matvec4(const float* __restrict__ Wp,
                                        const float* __restrict__ xs,
                                        float* __restrict__ dst, int t) {
    constexpr int nQ = N / 4;          // float4 column groups
    constexpr int kc = K / G;
    if (t < nQ * G) {
        int g = t / nQ;                // nQ is pow2 -> shift
        int j = t - g * nQ;
        const float4* W = (const float4*)Wp + (size_t)(g * kc) * nQ + j;
        const float* xp = xs + g * kc;
        float4 acc = make_float4(0.f, 0.f, 0.f, 0.f);
#pragma unroll 8
        for (int k = 0; k < kc; k++) {
            float4 w = W[(size_t)k * nQ];
            float xk = xp[k];
            acc.x = fmaf(w.x, xk, acc.x);
            acc.y = fmaf(w.y, xk, acc.y);
            acc.z = fmaf(w.z, xk, acc.z);
            acc.w = fmaf(w.w, xk, acc.w);
        }
        *((float4*)(dst + g * N) + j) = acc;
    }
}

// ---------------- main kernel ----------------

struct Args {
    const float *params, *disp;
    const float *embed_b, *embed_g, *embed_beta;
    const float *skip_b;
    const float *gates_b;
    const float *inln_g, *inln_b, *hln_g, *hln_b, *sln_g, *sln_b;
    const float *ab1, *aw2, *ab2;
    const float *rb1, *rb2, *rln_g, *rln_b;
    const float *ob1, *oln_g, *oln_b, *ow2, *ob2;
    const float *gw, *a1w, *r1w, *r2w, *ew, *sw, *o1w;
    float* out;
};

__global__ __launch_bounds__(1024) void xlstm_kernel(Args A) {
    const int tid = threadIdx.x;
    const int b = blockIdx.x;

    __shared__ __align__(16) float g4[4096];    // matvec partial scratch (16KB)
    __shared__ __align__(16) float xnhn[512];   // [xn,hn] / relu(r1) / head input
    __shared__ __align__(16) float cv[HH];      // staged c for a1 matvec
    __shared__ __align__(16) float hv[HH];      // staged h for r1 matvec
    __shared__ float sk[128];                   // skip activation
    __shared__ float xt[17];                    // timestep input features
    __shared__ float scrA[32], scrB[32];        // ping-pong reduction scratch

    // per-neuron registers (threads 0..255 own neuron `tid`)
    float xr = 0.f;
    float hreg[LL] = {0.f, 0.f, 0.f};
    float creg[LL] = {0.f, 0.f, 0.f};

    int rp = 0;   // reduction ping-pong counter (const-folds under unroll)
    auto RED = [&](float a, float bb) {
        float2 r = red2(a, bb, (rp & 1) ? scrB : scrA, tid);
        rp++;
        return r;
    };

    if (tid < 16) xt[1 + tid] = A.params[b * 16 + tid];
    __syncthreads();

    for (int t = 0; t < TT; t++) {
        if (tid == 0) xt[0] = A.disp[b * TT + t];
        __syncthreads();   // xt ready; g4/xnhn free from prev step

        // ---- embed (tid<256) & skip (256..383), each thread owns a column ----
        float ev = 0.f;
        if (tid < 256) {
            float a = 0.f;
#pragma unroll
            for (int k = 0; k < 17; k++) a = fmaf(A.ew[k * 256 + tid], xt[k], a);
            ev = a + A.embed_b[tid];
        } else if (tid < 384) {
            int j = tid - 256;
            float a = 0.f;
#pragma unroll
            for (int k = 0; k < 17; k++) a = fmaf(A.sw[k * 128 + j], xt[k], a);
            sk[j] = relu(a + A.skip_b[j]);
        }
        float2 f2 = RED(ev, ev * ev);   // tid>=256 contribute ev=0
        float mu = f2.x / HH;
        float inv = rsqrtf(f2.y / HH - mu * mu + LN_EPS);
        if (tid < 256) xr = relu((ev - mu) * inv * A.embed_g[tid] + A.embed_beta[tid]);

#pragma unroll
        for (int l = 0; l < LL; l++) {
            // ---- xn = LN(x), hn = LN(h); stage xnhn + cv ----
            float v = (tid < 256) ? xr : 0.f;
            f2 = RED(v, v * v);
            mu = f2.x / HH; inv = rsqrtf(f2.y / HH - mu * mu + LN_EPS);
            if (tid < 256)
                xnhn[tid] = (v - mu) * inv * A.inln_g[l * HH + tid] + A.inln_b[l * HH + tid];
            float hvv = (tid < 256) ? hreg[l] : 0.f;
            f2 = RED(hvv, hvv * hvv);
            mu = f2.x / HH; inv = rsqrtf(f2.y / HH - mu * mu + LN_EPS);
            if (tid < 256) {
                xnhn[HH + tid] = (hvv - mu) * inv * A.hln_g[l * HH + tid] + A.hln_b[l * HH + tid];
                cv[tid] = creg[l];
            }
            __syncthreads();

            // ---- imp = sigmoid(tanh(c @ aw1 + ab1) @ aw2 + ab2) ----
            matvec4<256, 256, 16>(A.a1w + (size_t)l * (256 * 256), cv, g4, tid);
            __syncthreads();
            v = 0.f;
            if (tid < 256) {
                float s = A.ab1[l * HH + tid];
#pragma unroll
                for (int g = 0; g < 16; g++) s += g4[g * 256 + tid];
                v = fast_tanh(s) * A.aw2[l * HH + tid];
            }
            f2 = RED(v, 0.f);
            float impv = fast_sigmoid(f2.x + A.ab2[l]);
            // RED's barrier separates imp's g4 reads from gates' g4 writes

            // ---- gates = [xn,hn] @ gates_w ----
            matvec4<512, 1024, 4>(A.gw + (size_t)l * (512 * 1024), xnhn, g4, tid);
            __syncthreads();
            v = 0.f;
            float og = 0.f;
            if (tid < 256) {
                const float* gb = A.gates_b + l * 1024;
                float si = gb[tid], sf = gb[256 + tid], sg = gb[512 + tid], so = gb[768 + tid];
#pragma unroll
                for (int g = 0; g < 4; g++) {
                    si += g4[g * 1024 + tid];
                    sf += g4[g * 1024 + 256 + tid];
                    sg += g4[g * 1024 + 512 + tid];
                    so += g4[g * 1024 + 768 + tid];
                }
                float ig = fast_sigmoid(si);
                float fg = fast_sigmoid(sf);
                float gg = fast_tanh(sg);
                og = fast_sigmoid(so);
                v = (fg * creg[l] + ig * gg) * impv;   // c_raw
            }
            f2 = RED(v, v * v);
            mu = f2.x / HH; inv = rsqrtf(f2.y / HH - mu * mu + LN_EPS);
            if (tid < 256) {
                float cn = (v - mu) * inv * A.sln_g[l * HH + tid] + A.sln_b[l * HH + tid];
                creg[l] = cn;
                float hn = og * fast_tanh(cn);
                hreg[l] = hn;
                hv[tid] = hn;
            }
            __syncthreads();   // hv staged (also: gates-epi g4 reads done before r1 writes)

            // ---- residual MLP ----
            matvec4<256, 512, 8>(A.r1w + (size_t)l * (256 * 512), hv, g4, tid);
            __syncthreads();
            if (tid < 512) {
                float s = A.rb1[l * 512 + tid];
#pragma unroll
                for (int g = 0; g < 8; g++) s += g4[g * 512 + tid];
                xnhn[tid] = relu(s);
            }
            __syncthreads();   // xnhn staged; g4 reads done before r2 writes

            matvec4<512, 256, 16>(A.r2w + (size_t)l * (512 * 256), xnhn, g4, tid);
            __syncthreads();
            v = 0.f;
            if (tid < 256) {
                float s = A.rb2[l * HH + tid] + hreg[l];
#pragma unroll
                for (int g = 0; g < 16; g++) s += g4[g * 256 + tid];
                v = s;
            }
            f2 = RED(v, v * v);
            mu = f2.x / HH; inv = rsqrtf(f2.y / HH - mu * mu + LN_EPS);
            if (tid < 256)
                xr = (v - mu) * inv * A.rln_g[l * HH + tid] + A.rln_b[l * HH + tid] + xr;
            // RED's barrier separates r2-epi g4 reads from next use
        }

        // ---- output head ----
        if (tid < 256) xnhn[tid] = xr;
        else if (tid < 384) xnhn[tid] = sk[tid - 256];
        __syncthreads();
        matvec4<384, 128, 32>(A.o1w, xnhn, g4, tid);   // kc=12
        __syncthreads();
        float v = 0.f;
        if (tid < 128) {
            float s = A.ob1[tid];
#pragma unroll
            for (int g = 0; g < 32; g++) s += g4[g * 128 + tid];
            v = s;
        }
        float2 f2o = RED(v, v * v);
        float muo = f2o.x / 128.f;
        float invo = rsqrtf(f2o.y / 128.f - muo * muo + LN_EPS);
        float contrib = 0.f;
        if (tid < 128)
            contrib = relu((v - muo) * invo * A.oln_g[tid] + A.oln_b[tid]) * A.ow2[tid];
        f2o = RED(contrib, 0.f);
        if (tid == 0) A.out[b * TT + t] = f2o.x + A.ob2[0];
        // top-of-loop barrier protects xt/g4/xnhn for the next step
    }
}

// ---------------- launch ----------------

extern "C" void kernel_launch(void* const* d_in, const int* in_sizes, int n_in,
                              void* d_out, int out_size, void* d_ws, size_t ws_size,
                              hipStream_t stream) {
    Args A;
    A.params     = (const float*)d_in[0];
    A.disp       = (const float*)d_in[1];
    A.ew         = (const float*)d_in[2];
    A.embed_b    = (const float*)d_in[3];
    A.embed_g    = (const float*)d_in[4];
    A.embed_beta = (const float*)d_in[5];
    A.sw         = (const float*)d_in[6];
    A.skip_b     = (const float*)d_in[7];
    A.gw         = (const float*)d_in[8];
    A.gates_b    = (const float*)d_in[9];
    A.inln_g     = (const float*)d_in[10];
    A.inln_b     = (const float*)d_in[11];
    A.hln_g      = (const float*)d_in[12];
    A.hln_b      = (const float*)d_in[13];
    A.sln_g      = (const float*)d_in[14];
    A.sln_b      = (const float*)d_in[15];
    A.a1w        = (const float*)d_in[16];
    A.ab1        = (const float*)d_in[17];
    A.aw2        = (const float*)d_in[18];
    A.ab2        = (const float*)d_in[19];
    A.r1w        = (const float*)d_in[20];
    A.rb1        = (const float*)d_in[21];
    A.r2w        = (const float*)d_in[22];
    A.rb2        = (const float*)d_in[23];
    A.rln_g      = (const float*)d_in[24];
    A.rln_b      = (const float*)d_in[25];
    A.o1w        = (const float*)d_in[26];
    A.ob1        = (const float*)d_in[27];
    A.oln_g      = (const float*)d_in[28];
    A.oln_b      = (const float*)d_in[29];
    A.ow2        = (const float*)d_in[30];
    A.ob2        = (const float*)d_in[31];
    A.out        = (float*)d_out;

    xlstm_kernel<<<BB, 1024, 0, stream>>>(A);
}